// Round 15
// baseline (70.636 us; speedup 1.0000x reference)
//
#include <hip/hip_runtime.h>

#define H 1536
#define BD 128
#define ROWS 16
#define NTHREADS 512
#define NBLOCKS 256    // 1 block/CU; 4 tiles of 16 rows per block

using f16x8 = _Float16 __attribute__((ext_vector_type(8)));
using f16x4 = _Float16 __attribute__((ext_vector_type(4)));
using f32x4 = float __attribute__((ext_vector_type(4)));
using i64x2 = long __attribute__((ext_vector_type(2)));

// Weights |w| <= 6e-4 are BELOW e4m3's denormal floor (2^-9) -> pre-scale by
// 2^14. t stored as t*2^7 in fp8; GEMM2 acc = x*2^21; y = acc*2^-21 + hs.
#define WD_SCALE 16384.0f           // 2^14
#define T8_SCALE (1.0f/128.0f)      // acc1(=t*2^14) * 2^-7 = t*2^7
#define X_SCALE  (1.0f/2097152.0f)  // 2^-21

// ---------------------------------------------------------------------------
// Kernel 0: pack weights fp32 -> fp8(e4m3, x2^14), pair-interleaved fragment
// order (R5-verified, unchanged).
// ---------------------------------------------------------------------------
__global__ __launch_bounds__(256) void pack_weights(const float* __restrict__ wd,
                                                    const float* __restrict__ wu,
                                                    char* __restrict__ wdp8,
                                                    char* __restrict__ wup8) {
    int f = blockIdx.x * 256 + threadIdx.x;   // 0..49151
    const float* src;
    char* dst;
    if (f < 24576) {
        int w = f / 3072, rem = f - w * 3072;
        int ph = rem >> 6, l = rem & 63;      // ph = frag index 0..47
        int row = 16 * w + (l & 15);
        int col = 32 * ph + 8 * (l >> 4);
        src = wd + (size_t)row * H + col;     // Wd is [128][1536]
        int p = ph >> 1, half = ph & 1;
        dst = wdp8 + (((size_t)(w * 24 + p) * 64 + l) * 16 + half * 8);
    } else {
        int g = f - 24576;
        int w = g / 3072, rem = g - w * 3072;
        int t2 = rem >> 6, l = rem & 63;      // t2 = nf*4 + kf
        int nf = t2 >> 2, kf = t2 & 3;
        int row = 192 * w + 16 * nf + (l & 15);
        int col = 32 * kf + 8 * (l >> 4);
        src = wu + (size_t)row * BD + col;    // Wu is [1536][128]
        int q = nf * 2 + (kf >> 1), half = kf & 1;
        dst = wup8 + (((size_t)(w * 24 + q) * 64 + l) * 16 + half * 8);
    }
    float4 v0 = reinterpret_cast<const float4*>(src)[0];
    float4 v1 = reinterpret_cast<const float4*>(src)[1];
    int i0 = __builtin_amdgcn_cvt_pk_fp8_f32(v0.x * WD_SCALE, v0.y * WD_SCALE, 0, false);
    i0     = __builtin_amdgcn_cvt_pk_fp8_f32(v0.z * WD_SCALE, v0.w * WD_SCALE, i0, true);
    int i1 = __builtin_amdgcn_cvt_pk_fp8_f32(v1.x * WD_SCALE, v1.y * WD_SCALE, 0, false);
    i1     = __builtin_amdgcn_cvt_pk_fp8_f32(v1.z * WD_SCALE, v1.w * WD_SCALE, i1, true);
    int2 st = {i0, i1};
    *reinterpret_cast<int2*>(dst) = st;
}

// ---------------------------------------------------------------------------
// Fused adapter, cross-tile LDS double-buffered pipeline (R15).
// Each block owns 4 consecutive 16-row tiles. While computing tile i (GEMM1 ->
// GEMM2+RMW -> final) from buffer cur, the 6 stage chunks of tile i+1 stream
// into buffer nxt (8-float liveness per chunk — R11's no-spill pattern).
// Phase bodies are byte-identical to R13 (verified). 3 barriers per tile.
// ---------------------------------------------------------------------------
__global__ __launch_bounds__(NTHREADS, 2) void fused_adapter(
    const float* __restrict__ hs,
    const char* __restrict__ wdp8,
    const char* __restrict__ wup8,
    const float* __restrict__ gamma,
    const float* __restrict__ beta,
    float* __restrict__ out)
{
    // P: hsb 49152 + hsa8 24576 | Q: same | tb8 2048 | red 1024 = 150528 B
    __shared__ alignas(16) char smem[150528];
    _Float16* hsbP = reinterpret_cast<_Float16*>(smem);
    char*     hsa8P = smem + 49152;
    _Float16* hsbQ = reinterpret_cast<_Float16*>(smem + 73728);
    char*     hsa8Q = smem + 122880;
    char*     tb8   = smem + 147456;                 // [4 frag][64][8B]
    float*    redS  = reinterpret_cast<float*>(smem + 149504);  // [8][16]
    float*    redQ  = redS + 128;

    const int tid  = threadIdx.x;
    const int lane = tid & 63;
    const int w    = tid >> 6;        // wave 0..7
    const int l15  = lane & 15;
    const int lk   = lane >> 4;       // 0..3
    const long row0 = (long)blockIdx.x * (4 * ROWS);

    const i64x2* wp2 = reinterpret_cast<const i64x2*>(wdp8) + (size_t)w * 24 * 64 + lane;
    const i64x2* up2 = reinterpret_cast<const i64x2*>(wup8) + (size_t)w * 24 * 64 + lane;

    // stage geometry: thread owns row sr, 8 cols at 8*scg + 256*chunk
    const int sr  = tid >> 5;         // 0..15
    const int scg = tid & 31;         // 0..31
    const int swzs = (sr & 7) << 3;   // hsb swizzle (fp16 elems, 16B granule)

    // store one chunk: fp16 -> hsb (residual) AND fp8 -> hsa8 (GEMM1 frags)
    auto store_chunk = [&](_Float16* hsb_, char* hsa8_, int c, float4 va, float4 vb) {
        int col8 = 8 * scg + 256 * c;
        f16x8 hv;
        hv[0] = (_Float16)va.x; hv[1] = (_Float16)va.y;
        hv[2] = (_Float16)va.z; hv[3] = (_Float16)va.w;
        hv[4] = (_Float16)vb.x; hv[5] = (_Float16)vb.y;
        hv[6] = (_Float16)vb.z; hv[7] = (_Float16)vb.w;
        *reinterpret_cast<f16x8*>(&hsb_[sr * H + (col8 ^ swzs)]) = hv;
        int c8 = scg + 32 * c;                    // 8-col group 0..191
        int kk = c8 >> 2, m = c8 & 3;
        int al = (16 * m + sr) ^ ((kk & 15) << 1);
        int j0 = __builtin_amdgcn_cvt_pk_fp8_f32(va.x, va.y, 0, false);
        j0     = __builtin_amdgcn_cvt_pk_fp8_f32(va.z, va.w, j0, true);
        int j1 = __builtin_amdgcn_cvt_pk_fp8_f32(vb.x, vb.y, 0, false);
        j1     = __builtin_amdgcn_cvt_pk_fp8_f32(vb.z, vb.w, j1, true);
        int2 stv = {j0, j1};
        *reinterpret_cast<int2*>(&hsa8_[(kk * 64 + al) * 8]) = stv;
    };

    // ---- prologue: stage tile 0 -> P (pairwise, 16-float liveness)
    {
        const float* srow0 = hs + (row0 + sr) * H + scg * 8;
#pragma unroll
        for (int pp = 0; pp < 3; ++pp) {
            const float4* p0 = reinterpret_cast<const float4*>(srow0 + 256 * (2 * pp));
            const float4* p1 = reinterpret_cast<const float4*>(srow0 + 256 * (2 * pp + 1));
            float4 a0 = p0[0], b0 = p0[1];
            float4 a1 = p1[0], b1 = p1[1];
            store_chunk(hsbP, hsa8P, 2 * pp, a0, b0);
            store_chunk(hsbP, hsa8P, 2 * pp + 1, a1, b1);
        }
    }
    __syncthreads();                                // tile 0 staged

#pragma unroll
    for (int t = 0; t < 4; ++t) {
        _Float16* chsb  = (t & 1) ? hsbQ : hsbP;
        char*     chsa8 = (t & 1) ? hsa8Q : hsa8P;
        _Float16* nhsb  = (t & 1) ? hsbP : hsbQ;
        char*     nhsa8 = (t & 1) ? hsa8P : hsa8Q;
        const bool stg = (t < 3);
        const float* hsblk = hs + (row0 + (long)t * ROWS) * H;
        float* outblk = out + (row0 + (long)t * ROWS) * H;
        const float* nsrow = stg ? hs + (row0 + (long)(t + 1) * ROWS + sr) * H + scg * 8
                                 : hsblk;   // unused when !stg

        float4 fA, fB;                 // stage chunk in flight
        if (stg) {
            const float4* p = reinterpret_cast<const float4*>(nsrow);
            fA = p[0]; fB = p[1];      // issue chunk 0
        }

        // ---- Wd prefetch (4-deep rotation)
        i64x2 bq[4];
#pragma unroll
        for (int i = 0; i < 4; ++i) bq[i] = wp2[i * 64];

        // ---- GEMM1 (fp8, swapped); tile fully staged, no internal barriers.
        // Stage slots after each pair-group: flush chunk g, issue chunk g+1.
        f32x4 accv[4] = {{0,0,0,0},{0,0,0,0},{0,0,0,0},{0,0,0,0}};
#pragma unroll
        for (int g = 0; g < 3; ++g) {
#pragma unroll
            for (int i = 0; i < 8; ++i) {       // pairs p = 8g..8g+7
                int p = 8 * g + i;
                int kk0 = 2 * p, kk1 = 2 * p + 1;
                long blo = *reinterpret_cast<const long*>(&chsa8[(kk0 * 64 + (lane ^ ((kk0 & 15) << 1))) * 8]);
                long bhi = *reinterpret_cast<const long*>(&chsa8[(kk1 * 64 + (lane ^ ((kk1 & 15) << 1))) * 8]);
                i64x2 b = bq[p & 3];
                if (p + 4 < 24) bq[p & 3] = wp2[(p + 4) * 64];
                f32x4 a = accv[p & 3];
                a = __builtin_amdgcn_mfma_f32_16x16x32_fp8_fp8(b[0], blo, a, 0, 0, 0);
                a = __builtin_amdgcn_mfma_f32_16x16x32_fp8_fp8(b[1], bhi, a, 0, 0, 0);
                accv[p & 3] = a;
            }
            if (stg) {                          // slots 0..2: flush g, issue g+1
                store_chunk(nhsb, nhsa8, g, fA, fB);
                const float4* p = reinterpret_cast<const float4*>(nsrow + 256 * (g + 1));
                fA = p[0]; fB = p[1];
            }
        }

        // ---- Wu prefetch (in flight across B2)
        i64x2 uq[4];
#pragma unroll
        for (int i = 0; i < 4; ++i) uq[i] = up2[i * 64];

        // ---- t -> tb8: ONE packed ds_write_b32 (swapped D layout)
        {
            f32x4 t0 = (accv[0] + accv[1]) + (accv[2] + accv[3]);
            int p0 = __builtin_amdgcn_cvt_pk_fp8_f32(t0[0] * T8_SCALE, t0[1] * T8_SCALE, 0, false);
            int p1 = __builtin_amdgcn_cvt_pk_fp8_f32(t0[2] * T8_SCALE, t0[3] * T8_SCALE, 0, false);
            unsigned word = (unsigned)(p0 & 0xFFFF) | ((unsigned)(p1 & 0xFFFF) << 16);
            int c0 = 16 * w + 4 * lk;
            int kf = c0 >> 5, hi = (c0 >> 3) & 3, off = c0 & 7;
            *reinterpret_cast<unsigned*>(&tb8[(kf * 64 + hi * 16 + l15) * 8 + off]) = word;
        }
        __syncthreads();                        // B2: tb8 ready

        long a2f8[4];
#pragma unroll
        for (int kf = 0; kf < 4; ++kf)
            a2f8[kf] = *reinterpret_cast<const long*>(&tb8[(kf * 64 + lane) * 8]);

        // ---- GEMM2 (fp8, swapped) + in-place y RMW on chsb + register stats.
        float s = 0.f, q = 0.f;
#pragma unroll
        for (int nf = 0; nf < 12; ++nf) {
            i64x2 u0 = uq[(2 * nf) & 3];
            i64x2 u1 = uq[(2 * nf + 1) & 3];
            if (2 * nf + 4 < 24) uq[(2 * nf) & 3]     = up2[(2 * nf + 4) * 64];
            if (2 * nf + 5 < 24) uq[(2 * nf + 1) & 3] = up2[(2 * nf + 5) * 64];
            f32x4 acc = {0.f, 0.f, 0.f, 0.f};
            acc = __builtin_amdgcn_mfma_f32_16x16x32_fp8_fp8(u0[0], a2f8[0], acc, 0, 0, 0);
            acc = __builtin_amdgcn_mfma_f32_16x16x32_fp8_fp8(u0[1], a2f8[1], acc, 0, 0, 0);
            acc = __builtin_amdgcn_mfma_f32_16x16x32_fp8_fp8(u1[0], a2f8[2], acc, 0, 0, 0);
            acc = __builtin_amdgcn_mfma_f32_16x16x32_fp8_fp8(u1[1], a2f8[3], acc, 0, 0, 0);
            int cx = 192 * w + 16 * nf + 4 * lk;
            int idx = l15 * H + (cx ^ ((l15 & 7) << 3));   // 4-aligned, 8B op
            f16x4 hv4 = *reinterpret_cast<const f16x4*>(&chsb[idx]);
            float y0 = acc[0] * X_SCALE + (float)hv4[0];
            float y1 = acc[1] * X_SCALE + (float)hv4[1];
            float y2 = acc[2] * X_SCALE + (float)hv4[2];
            float y3 = acc[3] * X_SCALE + (float)hv4[3];
            s += (y0 + y1) + (y2 + y3);
            q += (y0 * y0 + y1 * y1) + (y2 * y2 + y3 * y3);
            f16x4 yv;
            yv[0] = (_Float16)y0; yv[1] = (_Float16)y1;
            yv[2] = (_Float16)y2; yv[3] = (_Float16)y3;
            *reinterpret_cast<f16x4*>(&chsb[idx]) = yv;    // y overwrites hs
            if (stg && nf == 5) {              // slot 3: flush 3, issue 4
                store_chunk(nhsb, nhsa8, 3, fA, fB);
                const float4* p = reinterpret_cast<const float4*>(nsrow + 256 * 4);
                fA = p[0]; fB = p[1];
            }
            if (stg && nf == 11) {             // slot 4: flush 4, issue 5
                store_chunk(nhsb, nhsa8, 4, fA, fB);
                const float4* p = reinterpret_cast<const float4*>(nsrow + 256 * 5);
                fA = p[0]; fB = p[1];
            }
        }

        // ---- stats partials: (s,q) cover row l15; reduce over lk via shfl
        s += __shfl_xor(s, 16); s += __shfl_xor(s, 32);
        q += __shfl_xor(q, 16); q += __shfl_xor(q, 32);
        if (lane < 16) {
            redS[w * 16 + lane] = s;
            redQ[w * 16 + lane] = q;
        }
        __syncthreads();                        // B3: partials + y ready

        // ---- final: per-thread stats finish, normalize, coalesced stores.
        {
            const int fr  = tid >> 5;
            const int cid = tid & 31;
            const int fswz = (fr & 7) << 3;
            float S = 0.f, Q = 0.f;
#pragma unroll
            for (int ww = 0; ww < 8; ++ww) {
                S += redS[ww * 16 + fr];
                Q += redQ[ww * 16 + fr];
            }
            float mean = S * (1.0f / (float)H);
            float var  = Q * (1.0f / (float)H) - mean * mean;
            float rstd = rsqrtf(var + 1e-5f);
            float* orow = outblk + (long)fr * H;
#pragma unroll
            for (int k = 0; k < 6; ++k) {
                int col = 8 * (cid + 32 * k);
                f16x8 yv = *reinterpret_cast<const f16x8*>(&chsb[fr * H + (col ^ fswz)]);
                const float4* gp = reinterpret_cast<const float4*>(gamma + col);
                const float4* bp = reinterpret_cast<const float4*>(beta + col);
                float4 g0 = gp[0], g1 = gp[1];
                float4 b0 = bp[0], b1 = bp[1];
                float4 o0, o1;
                o0.x = ((float)yv[0] - mean) * rstd * g0.x + b0.x;
                o0.y = ((float)yv[1] - mean) * rstd * g0.y + b0.y;
                o0.z = ((float)yv[2] - mean) * rstd * g0.z + b0.z;
                o0.w = ((float)yv[3] - mean) * rstd * g0.w + b0.w;
                o1.x = ((float)yv[4] - mean) * rstd * g1.x + b1.x;
                o1.y = ((float)yv[5] - mean) * rstd * g1.y + b1.y;
                o1.z = ((float)yv[6] - mean) * rstd * g1.z + b1.z;
                o1.w = ((float)yv[7] - mean) * rstd * g1.w + b1.w;
                float4* op = reinterpret_cast<float4*>(orow + col);
                op[0] = o0;
                op[1] = o1;
                if (stg && k == 2) {           // slot 5: flush last chunk
                    store_chunk(nhsb, nhsa8, 5, fA, fB);
                }
            }
        }
        __syncthreads();                        // Bend: next tile staged; bufs handoff
    }
}

extern "C" void kernel_launch(void* const* d_in, const int* in_sizes, int n_in,
                              void* d_out, int out_size, void* d_ws, size_t ws_size,
                              hipStream_t stream) {
    const float* hs    = (const float*)d_in[0];
    const float* wd    = (const float*)d_in[1];
    const float* wu    = (const float*)d_in[2];
    const float* gam   = (const float*)d_in[3];
    const float* bet   = (const float*)d_in[4];
    float* out = (float*)d_out;

    char* wdp8 = (char*)d_ws;
    char* wup8 = (char*)d_ws + (size_t)128 * H;   // 196608 B each

    pack_weights<<<192, 256, 0, stream>>>(wd, wu, wdp8, wup8);
    fused_adapter<<<NBLOCKS, NTHREADS, 0, stream>>>(hs, wdp8, wup8, gam, bet, out);
}

// Round 16
// 61.991 us; speedup vs baseline: 1.1395x; 1.1395x over previous
//
#include <hip/hip_runtime.h>

#define H 1536
#define BD 128
#define ROWS 16
#define NTHREADS 512
#define NBLOCKS 1024   // 16384 rows / 16

using f16x8 = _Float16 __attribute__((ext_vector_type(8)));
using f16x4 = _Float16 __attribute__((ext_vector_type(4)));
using f32x4 = float __attribute__((ext_vector_type(4)));
using i64x2 = long __attribute__((ext_vector_type(2)));

// Weights |w| <= 6e-4 are BELOW e4m3's denormal floor (2^-9) -> pre-scale by
// 2^14. t stored as t*2^7 in fp8; GEMM2 acc = x*2^21; y = acc*2^-21 + hs.
#define WD_SCALE 16384.0f           // 2^14
#define T8_SCALE (1.0f/128.0f)      // acc1(=t*2^14) * 2^-7 = t*2^7
#define X_SCALE  (1.0f/2097152.0f)  // 2^-21

// LDS-only barrier: waits LDS ops, does NOT drain in-flight global loads
// (hipcc's __syncthreads emits s_waitcnt vmcnt(0) before s_barrier, killing
// every weight/stage prefetch). All barriers in this kernel protect only LDS
// data, so lgkmcnt(0) + raw s_barrier is sufficient (guide m201 pattern).
__device__ __forceinline__ void lds_barrier() {
    asm volatile("s_waitcnt lgkmcnt(0)" ::: "memory");
    __builtin_amdgcn_s_barrier();
}

// ---------------------------------------------------------------------------
// Kernel 0: pack weights fp32 -> fp8(e4m3, x2^14), pair-interleaved fragment
// order (R5-verified, unchanged).
// ---------------------------------------------------------------------------
__global__ __launch_bounds__(256) void pack_weights(const float* __restrict__ wd,
                                                    const float* __restrict__ wu,
                                                    char* __restrict__ wdp8,
                                                    char* __restrict__ wup8) {
    int f = blockIdx.x * 256 + threadIdx.x;   // 0..49151
    const float* src;
    char* dst;
    if (f < 24576) {
        int w = f / 3072, rem = f - w * 3072;
        int ph = rem >> 6, l = rem & 63;      // ph = frag index 0..47
        int row = 16 * w + (l & 15);
        int col = 32 * ph + 8 * (l >> 4);
        src = wd + (size_t)row * H + col;     // Wd is [128][1536]
        int p = ph >> 1, half = ph & 1;
        dst = wdp8 + (((size_t)(w * 24 + p) * 64 + l) * 16 + half * 8);
    } else {
        int g = f - 24576;
        int w = g / 3072, rem = g - w * 3072;
        int t2 = rem >> 6, l = rem & 63;      // t2 = nf*4 + kf
        int nf = t2 >> 2, kf = t2 & 3;
        int row = 192 * w + 16 * nf + (l & 15);
        int col = 32 * kf + 8 * (l >> 4);
        src = wu + (size_t)row * BD + col;    // Wu is [1536][128]
        int q = nf * 2 + (kf >> 1), half = kf & 1;
        dst = wup8 + (((size_t)(w * 24 + q) * 64 + l) * 16 + half * 8);
    }
    float4 v0 = reinterpret_cast<const float4*>(src)[0];
    float4 v1 = reinterpret_cast<const float4*>(src)[1];
    int i0 = __builtin_amdgcn_cvt_pk_fp8_f32(v0.x * WD_SCALE, v0.y * WD_SCALE, 0, false);
    i0     = __builtin_amdgcn_cvt_pk_fp8_f32(v0.z * WD_SCALE, v0.w * WD_SCALE, i0, true);
    int i1 = __builtin_amdgcn_cvt_pk_fp8_f32(v1.x * WD_SCALE, v1.y * WD_SCALE, 0, false);
    i1     = __builtin_amdgcn_cvt_pk_fp8_f32(v1.z * WD_SCALE, v1.w * WD_SCALE, i1, true);
    int2 st = {i0, i1};
    *reinterpret_cast<int2*>(dst) = st;
}

// ---------------------------------------------------------------------------
// Fused adapter = R13 (champion: fp8 GEMMs, fp16 hsb resident, hs read once,
// chunked stage pipelined into GEMM1, packed epilogues) with ALL barriers
// replaced by lds_barrier() so weight/stage prefetch survives across them.
// ---------------------------------------------------------------------------
__global__ __launch_bounds__(NTHREADS, 4) void fused_adapter(
    const float* __restrict__ hs,
    const char* __restrict__ wdp8,
    const char* __restrict__ wup8,
    const float* __restrict__ gamma,
    const float* __restrict__ beta,
    float* __restrict__ out)
{
    // 49152 hsb + 24576 hsa8 + 2048 tb8 + 1152 reductions = 76928 (2 blk/CU)
    __shared__ alignas(16) char smem[76928];
    _Float16* hsb = reinterpret_cast<_Float16*>(smem);            // [16][1536]
    char* hsa8    = smem + 49152;     // [48 frag][64 lane][8B] fp8 copy
    char* tb8     = smem + 73728;     // [4 frag][64][8B]
    float* redS   = reinterpret_cast<float*>(smem + 75776);       // [8][16]
    float* redQ   = redS + 128;
    float* statsM = redQ + 128;                                   // [16]
    float* statsR = statsM + 16;                                  // [16]

    const int tid  = threadIdx.x;
    const int lane = tid & 63;
    const int w    = tid >> 6;        // wave 0..7
    const int l15  = lane & 15;
    const int lk   = lane >> 4;       // 0..3
    const long row0 = (long)blockIdx.x * ROWS;
    const float* hsblk = hs + row0 * H;

    const i64x2* wp2 = reinterpret_cast<const i64x2*>(wdp8) + (size_t)w * 24 * 64 + lane;
    const i64x2* up2 = reinterpret_cast<const i64x2*>(wup8) + (size_t)w * 24 * 64 + lane;

    // stage geometry: thread owns row sr, 8 cols at 8*scg + 256*chunk
    const int sr  = tid >> 5;         // 0..15
    const int scg = tid & 31;         // 0..31
    const int swzs = (sr & 7) << 3;   // hsb swizzle (fp16 elems, 16B granule)
    const float* srow = hsblk + (long)sr * H + scg * 8;

    // store one chunk: fp16 -> hsb (residual) AND fp8 -> hsa8 (GEMM1 frags)
    auto store_chunk = [&](int c, float4 va, float4 vb) {
        int col8 = 8 * scg + 256 * c;
        f16x8 hv;
        hv[0] = (_Float16)va.x; hv[1] = (_Float16)va.y;
        hv[2] = (_Float16)va.z; hv[3] = (_Float16)va.w;
        hv[4] = (_Float16)vb.x; hv[5] = (_Float16)vb.y;
        hv[6] = (_Float16)vb.z; hv[7] = (_Float16)vb.w;
        *reinterpret_cast<f16x8*>(&hsb[sr * H + (col8 ^ swzs)]) = hv;
        int c8 = scg + 32 * c;                    // 8-col group 0..191
        int kk = c8 >> 2, m = c8 & 3;
        int al = (16 * m + sr) ^ ((kk & 15) << 1);
        int j0 = __builtin_amdgcn_cvt_pk_fp8_f32(va.x, va.y, 0, false);
        j0     = __builtin_amdgcn_cvt_pk_fp8_f32(va.z, va.w, j0, true);
        int j1 = __builtin_amdgcn_cvt_pk_fp8_f32(vb.x, vb.y, 0, false);
        j1     = __builtin_amdgcn_cvt_pk_fp8_f32(vb.z, vb.w, j1, true);
        int2 stv = {j0, j1};
        *reinterpret_cast<int2*>(&hsa8[(kk * 64 + al) * 8]) = stv;
    };

    // ---- Wd prefetch (4-deep rotation) + stage prologue (chunks 0,1)
    i64x2 bq[4];
#pragma unroll
    for (int i = 0; i < 4; ++i) bq[i] = wp2[i * 64];

    float4 A0, B0, A1, B1;            // two chunk slots (parity)
    A0 = reinterpret_cast<const float4*>(srow)[0];
    B0 = reinterpret_cast<const float4*>(srow)[1];
    A1 = reinterpret_cast<const float4*>(srow + 256)[0];
    B1 = reinterpret_cast<const float4*>(srow + 256)[1];
    store_chunk(0, A0, B0);
    lds_barrier();                    // chunk 0 visible (loads stay in flight)

    // ---- GEMM1 (fp8, swapped) pipelined over 6 chunks of 256 cols:
    // load chunk c+2 || 4 pair-MFMAs on chunk c || store chunk c+1.
    f32x4 accv[4] = {{0,0,0,0},{0,0,0,0},{0,0,0,0},{0,0,0,0}};
#pragma unroll
    for (int c = 0; c < 6; ++c) {
        if (c + 2 < 6) {
            const float4* p = reinterpret_cast<const float4*>(srow + 256 * (c + 2));
            if ((c & 1) == 0) { A0 = p[0]; B0 = p[1]; }
            else              { A1 = p[0]; B1 = p[1]; }
        }
#pragma unroll
        for (int i = 0; i < 4; ++i) { // pairs p = 4c..4c+3 (k-frags 8c..8c+7)
            int p = 4 * c + i;
            int kk0 = 2 * p, kk1 = 2 * p + 1;
            long blo = *reinterpret_cast<const long*>(&hsa8[(kk0 * 64 + (lane ^ ((kk0 & 15) << 1))) * 8]);
            long bhi = *reinterpret_cast<const long*>(&hsa8[(kk1 * 64 + (lane ^ ((kk1 & 15) << 1))) * 8]);
            i64x2 b = bq[p & 3];
            if (p + 4 < 24) bq[p & 3] = wp2[(p + 4) * 64];
            f32x4 a = accv[p & 3];
            a = __builtin_amdgcn_mfma_f32_16x16x32_fp8_fp8(b[0], blo, a, 0, 0, 0);
            a = __builtin_amdgcn_mfma_f32_16x16x32_fp8_fp8(b[1], bhi, a, 0, 0, 0);
            accv[p & 3] = a;
        }
        if (c + 1 < 6) {
            if (((c + 1) & 1) == 0) store_chunk(c + 1, A0, B0);
            else                    store_chunk(c + 1, A1, B1);
            lds_barrier();            // chunk c+1 visible
        }
    }

    // ---- Wu prefetch — now genuinely spans B2 (no vmcnt drain at barrier)
    i64x2 uq[4];
#pragma unroll
    for (int i = 0; i < 4; ++i) uq[i] = up2[i * 64];

    // ---- t -> tb8: ONE packed ds_write_b32 (swapped D layout, R8-verified)
    {
        f32x4 t0 = (accv[0] + accv[1]) + (accv[2] + accv[3]);
        int p0 = __builtin_amdgcn_cvt_pk_fp8_f32(t0[0] * T8_SCALE, t0[1] * T8_SCALE, 0, false);
        int p1 = __builtin_amdgcn_cvt_pk_fp8_f32(t0[2] * T8_SCALE, t0[3] * T8_SCALE, 0, false);
        unsigned word = (unsigned)(p0 & 0xFFFF) | ((unsigned)(p1 & 0xFFFF) << 16);
        int c0 = 16 * w + 4 * lk;
        int kf = c0 >> 5, hi = (c0 >> 3) & 3, off = c0 & 7;
        *reinterpret_cast<unsigned*>(&tb8[(kf * 64 + hi * 16 + l15) * 8 + off]) = word;
    }
    lds_barrier();                                  // B2: tb8 ready

    long a2f8[4];
#pragma unroll
    for (int kf = 0; kf < 4; ++kf)
        a2f8[kf] = *reinterpret_cast<const long*>(&tb8[(kf * 64 + lane) * 8]);

    // ---- GEMM2 (fp8, swapped) + in-place y RMW on hsb + register stats.
    // D: lane l15 = x-row, reg j = x-col cx+j. Wave w owns cols 192w..192w+191.
    float s = 0.f, q = 0.f;
#pragma unroll
    for (int nf = 0; nf < 12; ++nf) {
        i64x2 u0 = uq[(2 * nf) & 3];
        i64x2 u1 = uq[(2 * nf + 1) & 3];
        if (2 * nf + 4 < 24) uq[(2 * nf) & 3]     = up2[(2 * nf + 4) * 64];
        if (2 * nf + 5 < 24) uq[(2 * nf + 1) & 3] = up2[(2 * nf + 5) * 64];
        f32x4 acc = {0.f, 0.f, 0.f, 0.f};
        acc = __builtin_amdgcn_mfma_f32_16x16x32_fp8_fp8(u0[0], a2f8[0], acc, 0, 0, 0);
        acc = __builtin_amdgcn_mfma_f32_16x16x32_fp8_fp8(u0[1], a2f8[1], acc, 0, 0, 0);
        acc = __builtin_amdgcn_mfma_f32_16x16x32_fp8_fp8(u1[0], a2f8[2], acc, 0, 0, 0);
        acc = __builtin_amdgcn_mfma_f32_16x16x32_fp8_fp8(u1[1], a2f8[3], acc, 0, 0, 0);
        int cx = 192 * w + 16 * nf + 4 * lk;
        int idx = l15 * H + (cx ^ ((l15 & 7) << 3));   // 4-aligned, 8B op
        f16x4 hv4 = *reinterpret_cast<const f16x4*>(&hsb[idx]);
        float y0 = acc[0] * X_SCALE + (float)hv4[0];
        float y1 = acc[1] * X_SCALE + (float)hv4[1];
        float y2 = acc[2] * X_SCALE + (float)hv4[2];
        float y3 = acc[3] * X_SCALE + (float)hv4[3];
        s += (y0 + y1) + (y2 + y3);
        q += (y0 * y0 + y1 * y1) + (y2 * y2 + y3 * y3);
        f16x4 yv;
        yv[0] = (_Float16)y0; yv[1] = (_Float16)y1;
        yv[2] = (_Float16)y2; yv[3] = (_Float16)y3;
        *reinterpret_cast<f16x4*>(&hsb[idx]) = yv;     // y overwrites hs
    }

    // ---- stats: (s,q) cover row l15; reduce over lk via shfl, then 8 waves
    s += __shfl_xor(s, 16); s += __shfl_xor(s, 32);
    q += __shfl_xor(q, 16); q += __shfl_xor(q, 32);
    if (lane < 16) {
        redS[w * 16 + lane] = s;
        redQ[w * 16 + lane] = q;
    }
    lds_barrier();                                  // B3: partials + y ready
    if (tid < 16) {
        float S = 0.f, Q = 0.f;
#pragma unroll
        for (int ww = 0; ww < 8; ++ww) {
            S += redS[ww * 16 + tid];
            Q += redQ[ww * 16 + tid];
        }
        float mean = S * (1.0f / (float)H);
        float var  = Q * (1.0f / (float)H) - mean * mean;
        statsM[tid] = mean;
        statsR[tid] = rsqrtf(var + 1e-5f);
    }
    lds_barrier();                                  // B4: stats ready

    // ---- final: y from hsb (fp16), normalize, coalesced float4 stores
    {
        const int fr  = tid >> 5;
        const int cid = tid & 31;
        const int fswz = (fr & 7) << 3;
        float mean = statsM[fr];
        float rstd = statsR[fr];
        float* orow = out + (row0 + fr) * H;
#pragma unroll
        for (int k = 0; k < 6; ++k) {
            int col = 8 * (cid + 32 * k);
            f16x8 yv = *reinterpret_cast<const f16x8*>(&hsb[fr * H + (col ^ fswz)]);
            const float4* gp = reinterpret_cast<const float4*>(gamma + col);
            const float4* bp = reinterpret_cast<const float4*>(beta + col);
            float4 g0 = gp[0], g1 = gp[1];
            float4 b0 = bp[0], b1 = bp[1];
            float4 o0, o1;
            o0.x = ((float)yv[0] - mean) * rstd * g0.x + b0.x;
            o0.y = ((float)yv[1] - mean) * rstd * g0.y + b0.y;
            o0.z = ((float)yv[2] - mean) * rstd * g0.z + b0.z;
            o0.w = ((float)yv[3] - mean) * rstd * g0.w + b0.w;
            o1.x = ((float)yv[4] - mean) * rstd * g1.x + b1.x;
            o1.y = ((float)yv[5] - mean) * rstd * g1.y + b1.y;
            o1.z = ((float)yv[6] - mean) * rstd * g1.z + b1.z;
            o1.w = ((float)yv[7] - mean) * rstd * g1.w + b1.w;
            float4* op = reinterpret_cast<float4*>(orow + col);
            op[0] = o0;
            op[1] = o1;
        }
    }
}

extern "C" void kernel_launch(void* const* d_in, const int* in_sizes, int n_in,
                              void* d_out, int out_size, void* d_ws, size_t ws_size,
                              hipStream_t stream) {
    const float* hs    = (const float*)d_in[0];
    const float* wd    = (const float*)d_in[1];
    const float* wu    = (const float*)d_in[2];
    const float* gam   = (const float*)d_in[3];
    const float* bet   = (const float*)d_in[4];
    float* out = (float*)d_out;

    char* wdp8 = (char*)d_ws;
    char* wup8 = (char*)d_ws + (size_t)128 * H;   // 196608 B each

    pack_weights<<<192, 256, 0, stream>>>(wd, wu, wdp8, wup8);
    fused_adapter<<<NBLOCKS, NTHREADS, 0, stream>>>(hs, wdp8, wup8, gam, bet, out);
}

// Round 17
// 55.639 us; speedup vs baseline: 1.2695x; 1.1142x over previous
//
#include <hip/hip_runtime.h>

#define H 1536
#define BD 128
#define ROWS 16
#define NTHREADS 512
#define NBLOCKS 1024   // 16384 rows / 16

using f16x8 = _Float16 __attribute__((ext_vector_type(8)));
using f16x4 = _Float16 __attribute__((ext_vector_type(4)));
using f32x4 = float __attribute__((ext_vector_type(4)));
using i64x2 = long __attribute__((ext_vector_type(2)));

// Weights |w| <= 6e-4 are BELOW e4m3's denormal floor (2^-9) -> pre-scale by
// 2^14. t stored as t*2^7 in fp8; GEMM2 acc = x*2^21; y = acc*2^-21 + hs.
#define WD_SCALE 16384.0f           // 2^14
#define T8_SCALE (1.0f/128.0f)      // acc1(=t*2^14) * 2^-7 = t*2^7
#define X_SCALE  (1.0f/2097152.0f)  // 2^-21

// ---------------------------------------------------------------------------
// Kernel 0: pack weights fp32 -> fp8(e4m3, x2^14), pair-interleaved fragment
// order (R5-verified, unchanged).
// ---------------------------------------------------------------------------
__global__ __launch_bounds__(256) void pack_weights(const float* __restrict__ wd,
                                                    const float* __restrict__ wu,
                                                    char* __restrict__ wdp8,
                                                    char* __restrict__ wup8) {
    int f = blockIdx.x * 256 + threadIdx.x;   // 0..49151
    const float* src;
    char* dst;
    if (f < 24576) {
        int w = f / 3072, rem = f - w * 3072;
        int ph = rem >> 6, l = rem & 63;      // ph = frag index 0..47
        int row = 16 * w + (l & 15);
        int col = 32 * ph + 8 * (l >> 4);
        src = wd + (size_t)row * H + col;     // Wd is [128][1536]
        int p = ph >> 1, half = ph & 1;
        dst = wdp8 + (((size_t)(w * 24 + p) * 64 + l) * 16 + half * 8);
    } else {
        int g = f - 24576;
        int w = g / 3072, rem = g - w * 3072;
        int t2 = rem >> 6, l = rem & 63;      // t2 = nf*4 + kf
        int nf = t2 >> 2, kf = t2 & 3;
        int row = 192 * w + 16 * nf + (l & 15);
        int col = 32 * kf + 8 * (l >> 4);
        src = wu + (size_t)row * BD + col;    // Wu is [1536][128]
        int q = nf * 2 + (kf >> 1), half = kf & 1;
        dst = wup8 + (((size_t)(w * 24 + q) * 64 + l) * 16 + half * 8);
    }
    float4 v0 = reinterpret_cast<const float4*>(src)[0];
    float4 v1 = reinterpret_cast<const float4*>(src)[1];
    int i0 = __builtin_amdgcn_cvt_pk_fp8_f32(v0.x * WD_SCALE, v0.y * WD_SCALE, 0, false);
    i0     = __builtin_amdgcn_cvt_pk_fp8_f32(v0.z * WD_SCALE, v0.w * WD_SCALE, i0, true);
    int i1 = __builtin_amdgcn_cvt_pk_fp8_f32(v1.x * WD_SCALE, v1.y * WD_SCALE, 0, false);
    i1     = __builtin_amdgcn_cvt_pk_fp8_f32(v1.z * WD_SCALE, v1.w * WD_SCALE, i1, true);
    int2 st = {i0, i1};
    *reinterpret_cast<int2*>(dst) = st;
}

// ---------------------------------------------------------------------------
// Fused adapter = R5 (fp8 GEMMs, fp16 hsb resident, hs read ONCE)
//               + R11 (chunked stage pipelined into GEMM1)
//               + R8 (swapped-operand MFMAs -> packed epilogues).
// GEMM2 epilogue RMWs y = x + hs into hsb in place (8B fp16 ops) and carries
// stats in registers; final normalizes straight from hsb. 9 barriers.
// ---------------------------------------------------------------------------
__global__ __launch_bounds__(NTHREADS, 4) void fused_adapter(
    const float* __restrict__ hs,
    const char* __restrict__ wdp8,
    const char* __restrict__ wup8,
    const float* __restrict__ gamma,
    const float* __restrict__ beta,
    float* __restrict__ out)
{
    // 49152 hsb + 24576 hsa8 + 2048 tb8 + 1152 reductions = 76928 (2 blk/CU)
    __shared__ alignas(16) char smem[76928];
    _Float16* hsb = reinterpret_cast<_Float16*>(smem);            // [16][1536]
    char* hsa8    = smem + 49152;     // [48 frag][64 lane][8B] fp8 copy
    char* tb8     = smem + 73728;     // [4 frag][64][8B]
    float* redS   = reinterpret_cast<float*>(smem + 75776);       // [8][16]
    float* redQ   = redS + 128;
    float* statsM = redQ + 128;                                   // [16]
    float* statsR = statsM + 16;                                  // [16]

    const int tid  = threadIdx.x;
    const int lane = tid & 63;
    const int w    = tid >> 6;        // wave 0..7
    const int l15  = lane & 15;
    const int lk   = lane >> 4;       // 0..3
    const long row0 = (long)blockIdx.x * ROWS;
    const float* hsblk = hs + row0 * H;

    const i64x2* wp2 = reinterpret_cast<const i64x2*>(wdp8) + (size_t)w * 24 * 64 + lane;
    const i64x2* up2 = reinterpret_cast<const i64x2*>(wup8) + (size_t)w * 24 * 64 + lane;

    // stage geometry: thread owns row sr, 8 cols at 8*scg + 256*chunk
    const int sr  = tid >> 5;         // 0..15
    const int scg = tid & 31;         // 0..31
    const int swzs = (sr & 7) << 3;   // hsb swizzle (fp16 elems, 16B granule)
    const float* srow = hsblk + (long)sr * H + scg * 8;

    // store one chunk: fp16 -> hsb (residual) AND fp8 -> hsa8 (GEMM1 frags)
    auto store_chunk = [&](int c, float4 va, float4 vb) {
        int col8 = 8 * scg + 256 * c;
        f16x8 hv;
        hv[0] = (_Float16)va.x; hv[1] = (_Float16)va.y;
        hv[2] = (_Float16)va.z; hv[3] = (_Float16)va.w;
        hv[4] = (_Float16)vb.x; hv[5] = (_Float16)vb.y;
        hv[6] = (_Float16)vb.z; hv[7] = (_Float16)vb.w;
        *reinterpret_cast<f16x8*>(&hsb[sr * H + (col8 ^ swzs)]) = hv;
        int c8 = scg + 32 * c;                    // 8-col group 0..191
        int kk = c8 >> 2, m = c8 & 3;
        int al = (16 * m + sr) ^ ((kk & 15) << 1);
        int j0 = __builtin_amdgcn_cvt_pk_fp8_f32(va.x, va.y, 0, false);
        j0     = __builtin_amdgcn_cvt_pk_fp8_f32(va.z, va.w, j0, true);
        int j1 = __builtin_amdgcn_cvt_pk_fp8_f32(vb.x, vb.y, 0, false);
        j1     = __builtin_amdgcn_cvt_pk_fp8_f32(vb.z, vb.w, j1, true);
        int2 stv = {j0, j1};
        *reinterpret_cast<int2*>(&hsa8[(kk * 64 + al) * 8]) = stv;
    };

    // ---- Wd prefetch (4-deep rotation) + stage prologue (chunks 0,1)
    i64x2 bq[4];
#pragma unroll
    for (int i = 0; i < 4; ++i) bq[i] = wp2[i * 64];

    float4 A0, B0, A1, B1;            // two chunk slots (parity)
    A0 = reinterpret_cast<const float4*>(srow)[0];
    B0 = reinterpret_cast<const float4*>(srow)[1];
    A1 = reinterpret_cast<const float4*>(srow + 256)[0];
    B1 = reinterpret_cast<const float4*>(srow + 256)[1];
    store_chunk(0, A0, B0);
    __syncthreads();                  // chunk 0 visible

    // ---- GEMM1 (fp8, swapped) pipelined over 6 chunks of 256 cols:
    // load chunk c+2 || 4 pair-MFMAs on chunk c || store chunk c+1.
    f32x4 accv[4] = {{0,0,0,0},{0,0,0,0},{0,0,0,0},{0,0,0,0}};
#pragma unroll
    for (int c = 0; c < 6; ++c) {
        if (c + 2 < 6) {
            const float4* p = reinterpret_cast<const float4*>(srow + 256 * (c + 2));
            if ((c & 1) == 0) { A0 = p[0]; B0 = p[1]; }
            else              { A1 = p[0]; B1 = p[1]; }
        }
#pragma unroll
        for (int i = 0; i < 4; ++i) { // pairs p = 4c..4c+3 (k-frags 8c..8c+7)
            int p = 4 * c + i;
            int kk0 = 2 * p, kk1 = 2 * p + 1;
            long blo = *reinterpret_cast<const long*>(&hsa8[(kk0 * 64 + (lane ^ ((kk0 & 15) << 1))) * 8]);
            long bhi = *reinterpret_cast<const long*>(&hsa8[(kk1 * 64 + (lane ^ ((kk1 & 15) << 1))) * 8]);
            i64x2 b = bq[p & 3];
            if (p + 4 < 24) bq[p & 3] = wp2[(p + 4) * 64];
            f32x4 a = accv[p & 3];
            a = __builtin_amdgcn_mfma_f32_16x16x32_fp8_fp8(b[0], blo, a, 0, 0, 0);
            a = __builtin_amdgcn_mfma_f32_16x16x32_fp8_fp8(b[1], bhi, a, 0, 0, 0);
            accv[p & 3] = a;
        }
        if (c + 1 < 6) {
            if (((c + 1) & 1) == 0) store_chunk(c + 1, A0, B0);
            else                    store_chunk(c + 1, A1, B1);
            __syncthreads();          // chunk c+1 visible
        }
    }

    // ---- Wu prefetch (covers tb8 round-trip + barrier)
    i64x2 uq[4];
#pragma unroll
    for (int i = 0; i < 4; ++i) uq[i] = up2[i * 64];

    // ---- t -> tb8: ONE packed ds_write_b32 (swapped D layout, R8-verified)
    {
        f32x4 t0 = (accv[0] + accv[1]) + (accv[2] + accv[3]);
        int p0 = __builtin_amdgcn_cvt_pk_fp8_f32(t0[0] * T8_SCALE, t0[1] * T8_SCALE, 0, false);
        int p1 = __builtin_amdgcn_cvt_pk_fp8_f32(t0[2] * T8_SCALE, t0[3] * T8_SCALE, 0, false);
        unsigned word = (unsigned)(p0 & 0xFFFF) | ((unsigned)(p1 & 0xFFFF) << 16);
        int c0 = 16 * w + 4 * lk;
        int kf = c0 >> 5, hi = (c0 >> 3) & 3, off = c0 & 7;
        *reinterpret_cast<unsigned*>(&tb8[(kf * 64 + hi * 16 + l15) * 8 + off]) = word;
    }
    __syncthreads();                                // B2: tb8 ready

    long a2f8[4];
#pragma unroll
    for (int kf = 0; kf < 4; ++kf)
        a2f8[kf] = *reinterpret_cast<const long*>(&tb8[(kf * 64 + lane) * 8]);

    // ---- GEMM2 (fp8, swapped) + in-place y RMW on hsb + register stats.
    // D: lane l15 = x-row, reg j = x-col cx+j. Wave w owns cols 192w..192w+191.
    float s = 0.f, q = 0.f;
#pragma unroll
    for (int nf = 0; nf < 12; ++nf) {
        i64x2 u0 = uq[(2 * nf) & 3];
        i64x2 u1 = uq[(2 * nf + 1) & 3];
        if (2 * nf + 4 < 24) uq[(2 * nf) & 3]     = up2[(2 * nf + 4) * 64];
        if (2 * nf + 5 < 24) uq[(2 * nf + 1) & 3] = up2[(2 * nf + 5) * 64];
        f32x4 acc = {0.f, 0.f, 0.f, 0.f};
        acc = __builtin_amdgcn_mfma_f32_16x16x32_fp8_fp8(u0[0], a2f8[0], acc, 0, 0, 0);
        acc = __builtin_amdgcn_mfma_f32_16x16x32_fp8_fp8(u0[1], a2f8[1], acc, 0, 0, 0);
        acc = __builtin_amdgcn_mfma_f32_16x16x32_fp8_fp8(u1[0], a2f8[2], acc, 0, 0, 0);
        acc = __builtin_amdgcn_mfma_f32_16x16x32_fp8_fp8(u1[1], a2f8[3], acc, 0, 0, 0);
        int cx = 192 * w + 16 * nf + 4 * lk;
        int idx = l15 * H + (cx ^ ((l15 & 7) << 3));   // 4-aligned, 8B op
        f16x4 hv4 = *reinterpret_cast<const f16x4*>(&hsb[idx]);
        float y0 = acc[0] * X_SCALE + (float)hv4[0];
        float y1 = acc[1] * X_SCALE + (float)hv4[1];
        float y2 = acc[2] * X_SCALE + (float)hv4[2];
        float y3 = acc[3] * X_SCALE + (float)hv4[3];
        s += (y0 + y1) + (y2 + y3);
        q += (y0 * y0 + y1 * y1) + (y2 * y2 + y3 * y3);
        f16x4 yv;
        yv[0] = (_Float16)y0; yv[1] = (_Float16)y1;
        yv[2] = (_Float16)y2; yv[3] = (_Float16)y3;
        *reinterpret_cast<f16x4*>(&hsb[idx]) = yv;     // y overwrites hs
    }

    // ---- stats: (s,q) cover row l15; reduce over lk via shfl, then 8 waves
    s += __shfl_xor(s, 16); s += __shfl_xor(s, 32);
    q += __shfl_xor(q, 16); q += __shfl_xor(q, 32);
    if (lane < 16) {
        redS[w * 16 + lane] = s;
        redQ[w * 16 + lane] = q;
    }
    __syncthreads();                                // B3: partials + y ready
    if (tid < 16) {
        float S = 0.f, Q = 0.f;
#pragma unroll
        for (int ww = 0; ww < 8; ++ww) {
            S += redS[ww * 16 + tid];
            Q += redQ[ww * 16 + tid];
        }
        float mean = S * (1.0f / (float)H);
        float var  = Q * (1.0f / (float)H) - mean * mean;
        statsM[tid] = mean;
        statsR[tid] = rsqrtf(var + 1e-5f);
    }
    __syncthreads();                                // B4: stats ready

    // ---- final: y from hsb (fp16), normalize, coalesced float4 stores
    {
        const int fr  = tid >> 5;
        const int cid = tid & 31;
        const int fswz = (fr & 7) << 3;
        float mean = statsM[fr];
        float rstd = statsR[fr];
        float* orow = out + (row0 + fr) * H;
#pragma unroll
        for (int k = 0; k < 6; ++k) {
            int col = 8 * (cid + 32 * k);
            f16x8 yv = *reinterpret_cast<const f16x8*>(&hsb[fr * H + (col ^ fswz)]);
            const float4* gp = reinterpret_cast<const float4*>(gamma + col);
            const float4* bp = reinterpret_cast<const float4*>(beta + col);
            float4 g0 = gp[0], g1 = gp[1];
            float4 b0 = bp[0], b1 = bp[1];
            float4 o0, o1;
            o0.x = ((float)yv[0] - mean) * rstd * g0.x + b0.x;
            o0.y = ((float)yv[1] - mean) * rstd * g0.y + b0.y;
            o0.z = ((float)yv[2] - mean) * rstd * g0.z + b0.z;
            o0.w = ((float)yv[3] - mean) * rstd * g0.w + b0.w;
            o1.x = ((float)yv[4] - mean) * rstd * g1.x + b1.x;
            o1.y = ((float)yv[5] - mean) * rstd * g1.y + b1.y;
            o1.z = ((float)yv[6] - mean) * rstd * g1.z + b1.z;
            o1.w = ((float)yv[7] - mean) * rstd * g1.w + b1.w;
            float4* op = reinterpret_cast<float4*>(orow + col);
            op[0] = o0;
            op[1] = o1;
        }
    }
}

extern "C" void kernel_launch(void* const* d_in, const int* in_sizes, int n_in,
                              void* d_out, int out_size, void* d_ws, size_t ws_size,
                              hipStream_t stream) {
    const float* hs    = (const float*)d_in[0];
    const float* wd    = (const float*)d_in[1];
    const float* wu    = (const float*)d_in[2];
    const float* gam   = (const float*)d_in[3];
    const float* bet   = (const float*)d_in[4];
    float* out = (float*)d_out;

    char* wdp8 = (char*)d_ws;
    char* wup8 = (char*)d_ws + (size_t)128 * H;   // 196608 B each

    pack_weights<<<192, 256, 0, stream>>>(wd, wu, wdp8, wup8);
    fused_adapter<<<NBLOCKS, NTHREADS, 0, stream>>>(hs, wdp8, wup8, gam, bet, out);
}